// Round 1
// baseline (708.917 us; speedup 1.0000x reference)
//
#include <hip/hip_runtime.h>

// ATTConv: T=3, N=T+1=4 (3 neighbors + self), D=128, B=100000.
// emd[t,n] = h_neigh[t,n] for n<3, emd[t,3] = h_center[t].
// scores[t,n,b] = leakyrelu( dot(emd[t,n,b],w_e[t]) + dot(h_center[t,b],w_h[t]) + att_b[t] )
// attn = softmax over n; out[t,b,:] = sum_n attn * emd[t,n,b,:]
//
// Layout: one 32-lane half-wave per (t,b) row; each lane holds float4 (4 d's)
// of each of the 4 emd vectors. Memory-bound: ~768 MB total traffic.

#define TT 3
#define NN 4          // TT + 1
#define DD 128
#define NEG_SLOPE 0.01f

__global__ __launch_bounds__(256) void attconv_kernel(
    const float* __restrict__ h_center,  // (T,B,D)
    const float* __restrict__ h_neigh,   // (T,T,B,D)
    const float* __restrict__ att_w,     // (T,2D)
    const float* __restrict__ att_b,     // (T,)
    float* __restrict__ out,             // (T,B,D)
    int B, long long total_rows)
{
    long long tid  = (long long)blockIdx.x * blockDim.x + threadIdx.x;
    long long row  = tid >> 5;      // one (t,b) row per 32 lanes
    int lane = (int)(tid & 31);     // 0..31, covers 128 floats as float4
    if (row >= total_rows) return;
    int t = (int)(row / B);
    int b = (int)(row - (long long)t * B);

    // per-head weights: w_h = att_w[t][0:128], w_e = att_w[t][128:256]
    const float4* wv = (const float4*)(att_w + (size_t)t * 2 * DD);
    float4 wh = wv[lane];
    float4 we = wv[32 + lane];

    // load the 4 emd vectors (3 neighbors + center) — coalesced float4
    float4 e[NN];
    const float4* cen = (const float4*)(h_center + ((size_t)t * B + b) * DD);
    e[NN - 1] = cen[lane];
    #pragma unroll
    for (int n = 0; n < TT; ++n) {
        const float4* ng = (const float4*)(h_neigh + (((size_t)t * TT + n) * B + b) * DD);
        e[n] = ng[lane];
    }

    // partial dot products: s[0..3] = emd_n . w_e ; s[4] = center . w_h
    float s[NN + 1];
    #pragma unroll
    for (int n = 0; n < NN; ++n)
        s[n] = e[n].x * we.x + e[n].y * we.y + e[n].z * we.z + e[n].w * we.w;
    {
        float4 c = e[NN - 1];
        s[NN] = c.x * wh.x + c.y * wh.y + c.z * wh.z + c.w * wh.w;
    }

    // reduce over the 32 lanes of this half-wave (xor offsets < 32 never
    // cross the 32-lane half boundary within the 64-lane wave)
    #pragma unroll
    for (int off = 16; off > 0; off >>= 1) {
        #pragma unroll
        for (int k = 0; k < NN + 1; ++k)
            s[k] += __shfl_xor(s[k], off);
    }

    // scores + leaky relu + softmax over NN=4 (redundant per lane — cheap)
    float bias = att_b[t];
    float sc[NN];
    float m = -1e30f;
    #pragma unroll
    for (int n = 0; n < NN; ++n) {
        float x = s[n] + s[NN] + bias;
        x = (x >= 0.f) ? x : NEG_SLOPE * x;
        sc[n] = x;
        m = fmaxf(m, x);
    }
    float denom = 0.f;
    #pragma unroll
    for (int n = 0; n < NN; ++n) {
        sc[n] = __expf(sc[n] - m);
        denom += sc[n];
    }
    float inv = __frcp_rn(denom);

    float4 o = make_float4(0.f, 0.f, 0.f, 0.f);
    #pragma unroll
    for (int n = 0; n < NN; ++n) {
        float a = sc[n] * inv;
        o.x += a * e[n].x;
        o.y += a * e[n].y;
        o.z += a * e[n].z;
        o.w += a * e[n].w;
    }

    float4* op = (float4*)(out + ((size_t)t * B + b) * DD);
    op[lane] = o;
}

extern "C" void kernel_launch(void* const* d_in, const int* in_sizes, int n_in,
                              void* d_out, int out_size, void* d_ws, size_t ws_size,
                              hipStream_t stream) {
    const float* h_center = (const float*)d_in[0];  // (T,B,D)
    const float* h_neigh  = (const float*)d_in[1];  // (T,T,B,D)
    const float* att_w    = (const float*)d_in[2];  // (T,2D)
    const float* att_b    = (const float*)d_in[3];  // (T,)
    float* out = (float*)d_out;

    int B = in_sizes[0] / (TT * DD);                // 100000
    long long total_rows = (long long)TT * B;       // 300000
    long long total_threads = total_rows * 32;      // 9.6M
    int block = 256;
    long long grid = (total_threads + block - 1) / block;

    attconv_kernel<<<(dim3)(unsigned)grid, block, 0, stream>>>(
        h_center, h_neigh, att_w, att_b, out, B, total_rows);
}